// Round 15
// baseline (254.638 us; speedup 1.0000x reference)
//
#include <hip/hip_runtime.h>

// BandVQ forward: B=8, NB=3, D=512, T=2048, K=1024
// x:        [B, NB, D, T] f32
// codebook: [NB, K, D]    f32
// out: quantized [B,NB,D,T] f32 | codes [B,NB,T] (as float) | commit_loss (1 float)
//
// argmin_k |x-e_k|^2 = argmin_k (e2[k] - 2 x.e_k). Distance GEMM in ONE f16
// MFMA pass; rows with approx gap < MARGIN=0.10 are re-resolved exactly (fp64)
// over CANDIDATE 128-k tiles only.
// R15 = R14 with vq_gemm's K-loop reduced to ONE barrier per step:
//   vmcnt(0) -> barrier -> stage(s+1) -> ds_read(s)+MFMA
// WAR on buf[(s+1)&1] is protected by the barrier itself (stage issued after
// it; prior readers' ds_reads completed pre-barrier via compiler lgkmcnt).

#define B_ 8
#define NB_ 3
#define D_ 512
#define T_ 2048
#define K_ 1024
#define BN_ (B_*NB_)               // 24
#define ROWS_ (BN_*T_)             // 49152
#define Q_ELEMS_ ((size_t)BN_*D_*T_)  // 25165824
#define MARGIN_ 0.10f
#define WINDOW_ 0.30f
#define FLAGCAP_ 8192
#define RESCAN_BLOCKS_ 2048
#define QSCALE_ (1.0f / (float)Q_ELEMS_)

typedef __attribute__((ext_vector_type(4))) float f32x4;
typedef __attribute__((ext_vector_type(8))) _Float16 f16x8;
typedef __attribute__((ext_vector_type(4))) unsigned int u32x4;

__device__ inline unsigned short f2h(float f) {
    _Float16 h = (_Float16)f;
    return __builtin_bit_cast(unsigned short, h);
}
__device__ inline void gld16(const void* g, void* l) {
    __builtin_amdgcn_global_load_lds(
        (const __attribute__((address_space(1))) unsigned int*)g,
        (__attribute__((address_space(3))) unsigned int*)l, 16, 0, 0);
}

// ---------------- merged convert: y<8 -> x-transpose+f16+x2; y==8 -> cb+e2
__global__ __launch_bounds__(256) void convert_all(
    const float* __restrict__ x, const float* __restrict__ cb,
    unsigned short* __restrict__ Xh, unsigned short* __restrict__ Eh,
    float* __restrict__ e2, float* __restrict__ lossp,
    int* __restrict__ flag_cnt) {
    int tid = threadIdx.x;
    if (blockIdx.y == 8) {
        // ---- convert_e path: 32x24 = 768 blocks, 4 cb rows each
        int bid = blockIdx.x + 32 * blockIdx.z;
        if (bid == 0 && tid == 0) { *lossp = 0.f; *flag_cnt = 0; }
        int row = bid * 4 + (tid >> 6);   // 0..3071 = n*K + k
        int lane = tid & 63;
        const float* p = cb + (size_t)row * D_ + lane * 8;
        float v[8];
#pragma unroll
        for (int e = 0; e < 8; ++e) v[e] = p[e];
        double sum = 0.0;
#pragma unroll
        for (int e = 0; e < 8; ++e) sum += (double)v[e] * (double)v[e];
        unsigned int uh[4];
#pragma unroll
        for (int q = 0; q < 4; ++q)
            uh[q] = (unsigned)f2h(v[2*q]) | ((unsigned)f2h(v[2*q+1]) << 16);
        *(u32x4*)((char*)Eh + (size_t)row * 1024 + lane * 16) =
            u32x4{uh[0], uh[1], uh[2], uh[3]};
        for (int off = 32; off > 0; off >>= 1) sum += __shfl_down(sum, off, 64);
        if (lane == 0) e2[row] = (float)sum;
        return;
    }
    // ---- convert_x path
    int t0 = blockIdx.x * 64;       // 32 tiles
    int sl = blockIdx.y;            // 8 d-slices of 64
    int bn = blockIdx.z;            // 24
    int d0 = sl * 64;
    __shared__ float tile[64][69];
    int tt4 = (tid & 15) * 4, ddl = tid >> 4;
#pragma unroll
    for (int p = 0; p < 4; ++p) {
        int dd = ddl + 16 * p;
        float4 v = *(const float4*)&x[((size_t)bn * D_ + d0 + dd) * T_ + t0 + tt4];
        tile[dd][tt4 + 0] = v.x; tile[dd][tt4 + 1] = v.y;
        tile[dd][tt4 + 2] = v.z; tile[dd][tt4 + 3] = v.w;
    }
    __syncthreads();
    int tt = tid >> 2, cp = tid & 3;
    size_t rowbyte = ((size_t)bn * T_ + t0 + tt) * 1024 + (size_t)sl * 128;
    float s2 = 0.f;
#pragma unroll
    for (int cc = 0; cc < 2; ++cc) {
        int c = cp + 4 * cc;   // 4-lane group writes contiguous 64B
        unsigned int uh[4];
#pragma unroll
        for (int q = 0; q < 4; ++q) {
            float v0 = tile[c * 8 + 2*q][tt], v1 = tile[c * 8 + 2*q + 1][tt];
            s2 += v0 * v0 + v1 * v1;
            uh[q] = (unsigned)f2h(v0) | ((unsigned)f2h(v1) << 16);
        }
        *(u32x4*)((char*)Xh + rowbyte + c * 16) = u32x4{uh[0], uh[1], uh[2], uh[3]};
    }
    for (int off = 32; off > 0; off >>= 1) s2 += __shfl_down(s2, off, 64);
    __shared__ float ws4[4];
    if ((tid & 63) == 0) ws4[tid >> 6] = s2;
    __syncthreads();
    if (tid == 0)
        atomicAdd(lossp, (ws4[0] + ws4[1] + ws4[2] + ws4[3]) * QSCALE_);
}

// ------------------------------------------------------------- MFMA GEMM
// 128t x 128k tile, 256 thr / 4 waves (2m x 2n), BK=32, 2x16KB LDS bufs.
// ONE barrier per step: {vmcnt(0) -> barrier -> stage(s+1) -> read+MFMA}.
// Safety: (a) visibility -- vmcnt(0) precedes barrier, so when any wave
// passes, ALL waves' buf[s] loads have landed; (b) WAR -- stage targets
// buf[(s+1)&1]=buf[(s-1)&1]; every wave issued its step-(s-1) MFMAs before
// the barrier, and compiler-inserted lgkmcnt before MFMA guarantees those
// ds_reads completed. 4 blocks/CU; 64 VGPR.
__global__ __launch_bounds__(256, 4) void vq_gemm(
    const unsigned short* __restrict__ Xh, const unsigned short* __restrict__ Eh,
    const float* __restrict__ e2,
    float* __restrict__ pm1, float* __restrict__ pm2, int* __restrict__ pi1) {

    __shared__ char lds[32768];   // 2 bufs x {A 8KB, B 8KB}
    int tid = threadIdx.x;
    int lane = tid & 63, wid = tid >> 6;
    int bx = blockIdx.x, by = blockIdx.y, bn = blockIdx.z;
    int band = bn % NB_;
    int wm = wid >> 1, wn = wid & 1;
    int rl = lane & 15, cl = lane >> 4;

    // staging: waves 0-1 stage A (X rows), waves 2-3 stage B (E rows); 4KB each
    int is_b = wid >> 1;           // 0 or 1
    int wq = wid & 1;
    const char* srcm = is_b ? (const char*)Eh : (const char*)Xh;
    size_t rowbase = is_b ? ((size_t)band * K_ + (size_t)by * 128)
                          : ((size_t)bn * T_ + (size_t)bx * 128);
    // pre-swizzled global source chunk: (l&3) ^ ((l>>3)&3) within 64B row-slice
    const char* lane_src = srcm + (rowbase + wq * 64 + (lane >> 2)) * 1024
                         + (((lane & 3) ^ ((lane >> 3) & 3)) * 16);
    const int dstoff = is_b * 8192 + wq * 4096;
    // read-side swizzle (matches): 2 lanes/bank = conflict-free
    const int chunkoff = ((cl ^ ((rl >> 1) & 3)) * 16);

    // epilogue e2 values: load early (latency hides under the main loop)
    int kb = by * 128 + wn * 64 + rl;
    float ev[4];
#pragma unroll
    for (int n = 0; n < 4; ++n) ev[n] = e2[band * K_ + kb + n * 16];

    f32x4 acc[4][4];
#pragma unroll
    for (int m = 0; m < 4; ++m)
#pragma unroll
        for (int n = 0; n < 4; ++n) acc[m][n] = f32x4{0.f, 0.f, 0.f, 0.f};

    {   // prologue: stage s=0 into buf0
        char* dp = lds + dstoff;
#pragma unroll
        for (int q = 0; q < 4; ++q) gld16(lane_src + (size_t)q * 16384, dp + q * 1024);
    }

    for (int s = 0; s < 16; ++s) {
        asm volatile("s_waitcnt vmcnt(0)" ::: "memory");   // my buf[s] loads landed
        __builtin_amdgcn_s_barrier();   // all waves' loads landed; all prior reads done

        if (s < 15) {   // stage next step; flies during this step's compute
            const char* sp = lane_src + (size_t)(s + 1) * 64;
            char* dp = lds + ((s + 1) & 1) * 16384 + dstoff;
#pragma unroll
            for (int q = 0; q < 4; ++q) gld16(sp + (size_t)q * 16384, dp + q * 1024);
        }

        const char* base = lds + (s & 1) * 16384;
        f16x8 bh[4];
#pragma unroll
        for (int n = 0; n < 4; ++n)
            bh[n] = *(const f16x8*)(base + 8192 + (wn * 64 + n * 16 + rl) * 64 + chunkoff);
#pragma unroll
        for (int m = 0; m < 4; ++m) {
            f16x8 ah = *(const f16x8*)(base + (wm * 64 + m * 16 + rl) * 64 + chunkoff);
#pragma unroll
            for (int n = 0; n < 4; ++n)
                acc[m][n] = __builtin_amdgcn_mfma_f32_16x16x32_f16(ah, bh[n], acc[m][n], 0, 0, 0);
        }
    }

    // ---- epilogue: two-min fold (k ascending), butterfly over rl, merge wn
    float tm1[16], tm2[16];
    int ti[16];
#pragma unroll
    for (int m = 0; m < 4; ++m)
#pragma unroll
        for (int r = 0; r < 4; ++r) {
            int id = m * 4 + r;
            float a1 = 3.4e38f, a2 = 3.4e38f; int i1 = 0;
#pragma unroll
            for (int n = 0; n < 4; ++n) {
                float v = fmaf(-2.0f, acc[m][n][r], ev[n]);
                int k = kb + n * 16;
                a2 = fminf(fmaxf(v, a1), a2);   // new 2nd-min
                if (v < a1) { a1 = v; i1 = k; }
            }
            tm1[id] = a1; tm2[id] = a2; ti[id] = i1;
        }
#pragma unroll
    for (int id = 0; id < 16; ++id) {
#pragma unroll
        for (int st = 1; st < 16; st <<= 1) {
            float om1 = __shfl_xor(tm1[id], st, 64);
            float om2 = __shfl_xor(tm2[id], st, 64);
            int   oi  = __shfl_xor(ti[id],  st, 64);
            if (om1 < tm1[id] || (om1 == tm1[id] && oi < ti[id])) {
                tm2[id] = fminf(tm1[id], om2); tm1[id] = om1; ti[id] = oi;
            } else {
                tm2[id] = fminf(tm2[id], om1);
            }
        }
    }
    float* mm1 = (float*)lds;
    float* mm2 = (float*)(lds + 1024);
    int*   mi  = (int*)(lds + 2048);
    __syncthreads();
    if (rl == 0) {
#pragma unroll
        for (int m = 0; m < 4; ++m)
#pragma unroll
            for (int r = 0; r < 4; ++r) {
                int row = wm * 64 + m * 16 + cl * 4 + r;
                mm1[wn * 128 + row] = tm1[m * 4 + r];
                mm2[wn * 128 + row] = tm2[m * 4 + r];
                mi [wn * 128 + row] = ti [m * 4 + r];
            }
    }
    __syncthreads();
    if (tid < 128) {
        float m1 = mm1[tid], m2 = mm2[tid]; int i1 = mi[tid];
        float b1 = mm1[128 + tid], b2 = mm2[128 + tid]; int bi = mi[128 + tid];
        if (b1 < m1 || (b1 == m1 && bi < i1)) { m2 = fminf(m1, b2); m1 = b1; i1 = bi; }
        else m2 = fminf(m2, b1);
        size_t gr = (size_t)bn * T_ + (size_t)bx * 128 + tid;
        pm1[gr * 8 + by] = m1; pm2[gr * 8 + by] = m2; pi1[gr * 8 + by] = i1;
    }
}

// ----------------------------------------- finalize: merge, flag, fast loss
__global__ __launch_bounds__(256) void finalize_kernel(
    const float* __restrict__ pm1, const float* __restrict__ pm2,
    const int* __restrict__ pi1,
    float* __restrict__ outc, float* __restrict__ lossp,
    int* __restrict__ flag_cnt, int* __restrict__ flag_list) {
    int row = blockIdx.x * 256 + threadIdx.x;   // ROWS_ exact
    size_t r8 = (size_t)row * 8;
    float m1 = pm1[r8], m2 = pm2[r8]; int i1 = pi1[r8];
#pragma unroll
    for (int j = 1; j < 8; ++j) {
        float b1 = pm1[r8 + j], b2 = pm2[r8 + j]; int bi = pi1[r8 + j];
        if (b1 < m1) { m2 = fminf(m1, b2); m1 = b1; i1 = bi; }
        else m2 = fminf(m2, b1);
    }
    float lrow = m1;   // x^2 part already accumulated by convert_all
    if (m2 - m1 < MARGIN_) {
        int slot = atomicAdd(flag_cnt, 1);
        if (slot < FLAGCAP_) { flag_list[slot] = row; lrow = 0.f; }
        else outc[row] = (float)i1;   // overflow fallback (practically impossible)
    } else {
        outc[row] = (float)i1;
    }
    for (int off = 32; off > 0; off >>= 1) lrow += __shfl_down(lrow, off, 64);
    __shared__ float ws4[4];
    if ((threadIdx.x & 63) == 0) ws4[threadIdx.x >> 6] = lrow;
    __syncthreads();
    if (threadIdx.x == 0)
        atomicAdd(lossp, (ws4[0] + ws4[1] + ws4[2] + ws4[3]) * QSCALE_);
}

// --------------- rescan flagged rows exactly (fp64) over candidate tiles
__global__ __launch_bounds__(256) void rescan_kernel(
    const float* __restrict__ x, const float* __restrict__ cb,
    const float* __restrict__ pm1,
    const int* __restrict__ flag_cnt, const int* __restrict__ flag_list,
    float* __restrict__ outc, float* __restrict__ lossp) {
    int tid = threadIdx.x;
    int cnt = *flag_cnt; if (cnt > FLAGCAP_) cnt = FLAGCAP_;
    __shared__ float xsh[D_];
    __shared__ float qm[8];
    __shared__ double rv[256];
    __shared__ int    ri[256];
    for (int i = blockIdx.x; i < cnt; i += RESCAN_BLOCKS_) {
        int row = flag_list[i];
        int bn = row / T_, t = row % T_;
        int band = bn % NB_;
        __syncthreads();
        if (tid < 8) qm[tid] = pm1[(size_t)row * 8 + tid];
        for (int d = tid; d < D_; d += 256)
            xsh[d] = x[((size_t)bn * D_ + d) * T_ + t];
        __syncthreads();
        float gmin = qm[0];
#pragma unroll
        for (int j = 1; j < 8; ++j) gmin = fminf(gmin, qm[j]);
        // exact row x^2 (to back out convert_all's contribution)
        double px2 = 0.0;
        for (int d = tid; d < D_; d += 256) px2 += (double)xsh[d] * (double)xsh[d];
        rv[tid] = px2;
        __syncthreads();
        for (int s2 = 128; s2 > 0; s2 >>= 1) {
            if (tid < s2) rv[tid] += rv[tid + s2];
            __syncthreads();
        }
        double x2row = rv[0];
        __syncthreads();

        int kq = tid >> 1, half = tid & 1;
        double best = 1e300; int bi = K_;
        for (int j = 0; j < 8; ++j) {
            if (qm[j] > gmin + WINDOW_) continue;   // uniform branch (shared)
            int k = j * 128 + kq;
            const float* cr = cb + ((size_t)band * K_ + k) * D_ + half * 256;
            const float* xr = xsh + half * 256;
            double s = 0.0;
#pragma unroll 4
            for (int d = 0; d < 256; d += 4) {
                float4 c4 = *(const float4*)(cr + d);
                double e0 = (double)xr[d]     - (double)c4.x;
                double e1 = (double)xr[d + 1] - (double)c4.y;
                double e2v = (double)xr[d + 2] - (double)c4.z;
                double e3 = (double)xr[d + 3] - (double)c4.w;
                s += e0 * e0 + e1 * e1 + e2v * e2v + e3 * e3;
            }
            s += __shfl_xor(s, 1, 64);   // combine halves; both lanes hold full dist
            if (s < best || (s == best && k < bi)) { best = s; bi = k; }
        }
        rv[tid] = best; ri[tid] = bi;
        __syncthreads();
        for (int s2 = 128; s2 > 0; s2 >>= 1) {
            if (tid < s2) {
                if (rv[tid + s2] < rv[tid] ||
                    (rv[tid + s2] == rv[tid] && ri[tid + s2] < ri[tid])) {
                    rv[tid] = rv[tid + s2]; ri[tid] = ri[tid + s2];
                }
            }
            __syncthreads();
        }
        if (tid == 0) {
            outc[row] = (float)ri[0];
            atomicAdd(lossp, (float)((rv[0] - x2row) * (double)QSCALE_));
        }
        __syncthreads();
    }
}

// ------------------- gather + write outq: 256t x 16d blocks, 1KB HBM runs
__global__ __launch_bounds__(256) void gather_out(
    const float* __restrict__ cb, const float* __restrict__ outc,
    float* __restrict__ outq) {
    int t0 = blockIdx.x * 256;   // 8
    int d0 = blockIdx.y * 16;    // 32
    int bn = blockIdx.z;         // 24
    int band = bn % NB_;
    int tid = threadIdx.x;
    __shared__ int csh[256];
    __shared__ float qsh[16][260];   // [d][t]
    csh[tid] = (int)outc[(size_t)bn * T_ + t0 + tid];
    __syncthreads();
    const float* cbb = cb + (size_t)band * K_ * D_ + d0;
    int tq = tid >> 2, dq = (tid & 3) * 4;
#pragma unroll
    for (int p = 0; p < 4; ++p) {
        int t = tq + p * 64;
        float4 v = *(const float4*)(cbb + (size_t)csh[t] * D_ + dq);
        qsh[dq + 0][t] = v.x; qsh[dq + 1][t] = v.y;
        qsh[dq + 2][t] = v.z; qsh[dq + 3][t] = v.w;
    }
    __syncthreads();
    int wv = tid >> 6, ln = tid & 63;
#pragma unroll
    for (int j = 0; j < 4; ++j) {
        int dd = wv * 4 + j;
        *(float4*)&outq[((size_t)bn * D_ + d0 + dd) * T_ + t0 + ln * 4] =
            *(const float4*)&qsh[dd][ln * 4];
    }
}

// ---------------------------------------------------------------- launcher
extern "C" void kernel_launch(void* const* d_in, const int* in_sizes, int n_in,
                              void* d_out, int out_size, void* d_ws, size_t ws_size,
                              hipStream_t stream) {
    (void)in_sizes; (void)n_in; (void)out_size; (void)ws_size;
    const float* x  = (const float*)d_in[0];
    const float* cb = (const float*)d_in[1];
    float* out = (float*)d_out;

    float* outq  = out;                       // [B,NB,D,T]
    float* outc  = out + Q_ELEMS_;            // [B,NB,T] as float
    float* lossp = out + Q_ELEMS_ + ROWS_;    // scalar

    // f16 x lives in the (not-yet-written) quantized output region (50.3 MB =
    // first 12,582,912 floats). GEMM partials live after it, also inside outq
    // (read by finalize/rescan, overwritten only by gather_out at the end).
    unsigned short* Xh = (unsigned short*)d_out;
    float* pm1 = out + 13107200;                   // 393216 floats
    float* pm2 = pm1 + (size_t)ROWS_ * 8;          // 393216
    int*   pi1 = (int*)(pm2 + (size_t)ROWS_ * 8);  // 393216 (ends ~14.3M < 25.1M)

    char* ws = (char*)d_ws;
    unsigned short* Eh = (unsigned short*)ws;                    // 3 MiB
    float* e2  = (float*)(Eh + (size_t)NB_ * K_ * D_);           // 12 KiB
    int*   flag_cnt  = (int*)(e2 + NB_ * K_);                    // 4 B
    int*   flag_list = flag_cnt + 1;                             // 32 KiB

    convert_all<<<dim3(32, 9, 24), dim3(256), 0, stream>>>(
        x, cb, Xh, Eh, e2, lossp, flag_cnt);
    vq_gemm<<<dim3(16, 8, 24), dim3(256), 0, stream>>>(Xh, Eh, e2, pm1, pm2, pi1);
    finalize_kernel<<<dim3(ROWS_ / 256), dim3(256), 0, stream>>>(
        pm1, pm2, pi1, outc, lossp, flag_cnt, flag_list);
    rescan_kernel<<<dim3(RESCAN_BLOCKS_), dim3(256), 0, stream>>>(
        x, cb, pm1, flag_cnt, flag_list, outc, lossp);
    gather_out<<<dim3(8, 32, 24), dim3(256), 0, stream>>>(cb, outc, outq);
}

// Round 16
// 252.163 us; speedup vs baseline: 1.0098x; 1.0098x over previous
//
#include <hip/hip_runtime.h>

// BandVQ forward: B=8, NB=3, D=512, T=2048, K=1024
// x:        [B, NB, D, T] f32
// codebook: [NB, K, D]    f32
// out: quantized [B,NB,D,T] f32 | codes [B,NB,T] (as float) | commit_loss (1 float)
//
// argmin_k |x-e_k|^2 = argmin_k (e2[k] - 2 x.e_k). Distance GEMM in ONE f16
// MFMA pass; rows with approx gap < MARGIN=0.10 are re-resolved exactly (fp64)
// over CANDIDATE 128-k tiles only.
// R16 = R14 exact revert (best-known state, 252.3 us):
//  - vq_gemm: R10 two-barrier counted-vmcnt loop (133 us; 8 variants tried,
//    all regressed or tied -- latency-bound plateau of this structure)
//  - convert_all: merged x+cb convert (R13)
//  - gather_out: 256t x 16d, 1KB contiguous HBM writes (R14)

#define B_ 8
#define NB_ 3
#define D_ 512
#define T_ 2048
#define K_ 1024
#define BN_ (B_*NB_)               // 24
#define ROWS_ (BN_*T_)             // 49152
#define Q_ELEMS_ ((size_t)BN_*D_*T_)  // 25165824
#define MARGIN_ 0.10f
#define WINDOW_ 0.30f
#define FLAGCAP_ 8192
#define RESCAN_BLOCKS_ 2048
#define QSCALE_ (1.0f / (float)Q_ELEMS_)

typedef __attribute__((ext_vector_type(4))) float f32x4;
typedef __attribute__((ext_vector_type(8))) _Float16 f16x8;
typedef __attribute__((ext_vector_type(4))) unsigned int u32x4;

__device__ inline unsigned short f2h(float f) {
    _Float16 h = (_Float16)f;
    return __builtin_bit_cast(unsigned short, h);
}
__device__ inline void gld16(const void* g, void* l) {
    __builtin_amdgcn_global_load_lds(
        (const __attribute__((address_space(1))) unsigned int*)g,
        (__attribute__((address_space(3))) unsigned int*)l, 16, 0, 0);
}

// ---------------- merged convert: y<8 -> x-transpose+f16+x2; y==8 -> cb+e2
__global__ __launch_bounds__(256) void convert_all(
    const float* __restrict__ x, const float* __restrict__ cb,
    unsigned short* __restrict__ Xh, unsigned short* __restrict__ Eh,
    float* __restrict__ e2, float* __restrict__ lossp,
    int* __restrict__ flag_cnt) {
    int tid = threadIdx.x;
    if (blockIdx.y == 8) {
        // ---- convert_e path: 32x24 = 768 blocks, 4 cb rows each
        int bid = blockIdx.x + 32 * blockIdx.z;
        if (bid == 0 && tid == 0) { *lossp = 0.f; *flag_cnt = 0; }
        int row = bid * 4 + (tid >> 6);   // 0..3071 = n*K + k
        int lane = tid & 63;
        const float* p = cb + (size_t)row * D_ + lane * 8;
        float v[8];
#pragma unroll
        for (int e = 0; e < 8; ++e) v[e] = p[e];
        double sum = 0.0;
#pragma unroll
        for (int e = 0; e < 8; ++e) sum += (double)v[e] * (double)v[e];
        unsigned int uh[4];
#pragma unroll
        for (int q = 0; q < 4; ++q)
            uh[q] = (unsigned)f2h(v[2*q]) | ((unsigned)f2h(v[2*q+1]) << 16);
        *(u32x4*)((char*)Eh + (size_t)row * 1024 + lane * 16) =
            u32x4{uh[0], uh[1], uh[2], uh[3]};
        for (int off = 32; off > 0; off >>= 1) sum += __shfl_down(sum, off, 64);
        if (lane == 0) e2[row] = (float)sum;
        return;
    }
    // ---- convert_x path
    int t0 = blockIdx.x * 64;       // 32 tiles
    int sl = blockIdx.y;            // 8 d-slices of 64
    int bn = blockIdx.z;            // 24
    int d0 = sl * 64;
    __shared__ float tile[64][69];
    int tt4 = (tid & 15) * 4, ddl = tid >> 4;
#pragma unroll
    for (int p = 0; p < 4; ++p) {
        int dd = ddl + 16 * p;
        float4 v = *(const float4*)&x[((size_t)bn * D_ + d0 + dd) * T_ + t0 + tt4];
        tile[dd][tt4 + 0] = v.x; tile[dd][tt4 + 1] = v.y;
        tile[dd][tt4 + 2] = v.z; tile[dd][tt4 + 3] = v.w;
    }
    __syncthreads();
    int tt = tid >> 2, cp = tid & 3;
    size_t rowbyte = ((size_t)bn * T_ + t0 + tt) * 1024 + (size_t)sl * 128;
    float s2 = 0.f;
#pragma unroll
    for (int cc = 0; cc < 2; ++cc) {
        int c = cp + 4 * cc;   // 4-lane group writes contiguous 64B
        unsigned int uh[4];
#pragma unroll
        for (int q = 0; q < 4; ++q) {
            float v0 = tile[c * 8 + 2*q][tt], v1 = tile[c * 8 + 2*q + 1][tt];
            s2 += v0 * v0 + v1 * v1;
            uh[q] = (unsigned)f2h(v0) | ((unsigned)f2h(v1) << 16);
        }
        *(u32x4*)((char*)Xh + rowbyte + c * 16) = u32x4{uh[0], uh[1], uh[2], uh[3]};
    }
    for (int off = 32; off > 0; off >>= 1) s2 += __shfl_down(s2, off, 64);
    __shared__ float ws4[4];
    if ((tid & 63) == 0) ws4[tid >> 6] = s2;
    __syncthreads();
    if (tid == 0)
        atomicAdd(lossp, (ws4[0] + ws4[1] + ws4[2] + ws4[3]) * QSCALE_);
}

// ------------------------------------------------------------- MFMA GEMM
// 128t x 128k tile, 256 thr / 4 waves (2m x 2n), BK=32, 2x16KB LDS bufs.
// 1-deep counted-vmcnt; 4 blocks/CU; 64 VGPR. R10-proven config: 133 us.
__global__ __launch_bounds__(256, 4) void vq_gemm(
    const unsigned short* __restrict__ Xh, const unsigned short* __restrict__ Eh,
    const float* __restrict__ e2,
    float* __restrict__ pm1, float* __restrict__ pm2, int* __restrict__ pi1) {

    __shared__ char lds[32768];   // 2 bufs x {A 8KB, B 8KB}
    int tid = threadIdx.x;
    int lane = tid & 63, wid = tid >> 6;
    int bx = blockIdx.x, by = blockIdx.y, bn = blockIdx.z;
    int band = bn % NB_;
    int wm = wid >> 1, wn = wid & 1;
    int rl = lane & 15, cl = lane >> 4;

    // staging: waves 0-1 stage A (X rows), waves 2-3 stage B (E rows); 4KB each
    int is_b = wid >> 1;           // 0 or 1
    int wq = wid & 1;
    const char* srcm = is_b ? (const char*)Eh : (const char*)Xh;
    size_t rowbase = is_b ? ((size_t)band * K_ + (size_t)by * 128)
                          : ((size_t)bn * T_ + (size_t)bx * 128);
    // pre-swizzled global source chunk: (l&3) ^ ((l>>3)&3) within 64B row-slice
    const char* lane_src = srcm + (rowbase + wq * 64 + (lane >> 2)) * 1024
                         + (((lane & 3) ^ ((lane >> 3) & 3)) * 16);
    const int dstoff = is_b * 8192 + wq * 4096;
    // read-side swizzle (matches): 2 lanes/bank = conflict-free
    const int chunkoff = ((cl ^ ((rl >> 1) & 3)) * 16);

    // epilogue e2 values: load early (latency hides under the main loop)
    int kb = by * 128 + wn * 64 + rl;
    float ev[4];
#pragma unroll
    for (int n = 0; n < 4; ++n) ev[n] = e2[band * K_ + kb + n * 16];

    f32x4 acc[4][4];
#pragma unroll
    for (int m = 0; m < 4; ++m)
#pragma unroll
        for (int n = 0; n < 4; ++n) acc[m][n] = f32x4{0.f, 0.f, 0.f, 0.f};

    {   // prologue: stage s=0 into buf0
        char* dp = lds + dstoff;
#pragma unroll
        for (int q = 0; q < 4; ++q) gld16(lane_src + (size_t)q * 16384, dp + q * 1024);
    }

    for (int s = 0; s < 16; ++s) {
        if (s < 15) {   // issue next-step staging; in flight across this compute
            const char* sp = lane_src + (size_t)(s + 1) * 64;
            char* dp = lds + ((s + 1) & 1) * 16384 + dstoff;
#pragma unroll
            for (int q = 0; q < 4; ++q) gld16(sp + (size_t)q * 16384, dp + q * 1024);
            asm volatile("s_waitcnt vmcnt(4)" ::: "memory");   // buf[s] landed
        } else {
            asm volatile("s_waitcnt vmcnt(0)" ::: "memory");
        }
        __builtin_amdgcn_s_barrier();                          // cur buf ready

        const char* base = lds + (s & 1) * 16384;
        f16x8 bh[4];
#pragma unroll
        for (int n = 0; n < 4; ++n)
            bh[n] = *(const f16x8*)(base + 8192 + (wn * 64 + n * 16 + rl) * 64 + chunkoff);
#pragma unroll
        for (int m = 0; m < 4; ++m) {
            f16x8 ah = *(const f16x8*)(base + (wm * 64 + m * 16 + rl) * 64 + chunkoff);
#pragma unroll
            for (int n = 0; n < 4; ++n)
                acc[m][n] = __builtin_amdgcn_mfma_f32_16x16x32_f16(ah, bh[n], acc[m][n], 0, 0, 0);
        }
        asm volatile("s_waitcnt lgkmcnt(0)" ::: "memory");     // my ds_reads done
        __builtin_amdgcn_s_barrier();      // buf[s] may now be overwritten
    }

    // ---- epilogue: two-min fold (k ascending), butterfly over rl, merge wn
    float tm1[16], tm2[16];
    int ti[16];
#pragma unroll
    for (int m = 0; m < 4; ++m)
#pragma unroll
        for (int r = 0; r < 4; ++r) {
            int id = m * 4 + r;
            float a1 = 3.4e38f, a2 = 3.4e38f; int i1 = 0;
#pragma unroll
            for (int n = 0; n < 4; ++n) {
                float v = fmaf(-2.0f, acc[m][n][r], ev[n]);
                int k = kb + n * 16;
                a2 = fminf(fmaxf(v, a1), a2);   // new 2nd-min
                if (v < a1) { a1 = v; i1 = k; }
            }
            tm1[id] = a1; tm2[id] = a2; ti[id] = i1;
        }
#pragma unroll
    for (int id = 0; id < 16; ++id) {
#pragma unroll
        for (int st = 1; st < 16; st <<= 1) {
            float om1 = __shfl_xor(tm1[id], st, 64);
            float om2 = __shfl_xor(tm2[id], st, 64);
            int   oi  = __shfl_xor(ti[id],  st, 64);
            if (om1 < tm1[id] || (om1 == tm1[id] && oi < ti[id])) {
                tm2[id] = fminf(tm1[id], om2); tm1[id] = om1; ti[id] = oi;
            } else {
                tm2[id] = fminf(tm2[id], om1);
            }
        }
    }
    float* mm1 = (float*)lds;
    float* mm2 = (float*)(lds + 1024);
    int*   mi  = (int*)(lds + 2048);
    __syncthreads();
    if (rl == 0) {
#pragma unroll
        for (int m = 0; m < 4; ++m)
#pragma unroll
            for (int r = 0; r < 4; ++r) {
                int row = wm * 64 + m * 16 + cl * 4 + r;
                mm1[wn * 128 + row] = tm1[m * 4 + r];
                mm2[wn * 128 + row] = tm2[m * 4 + r];
                mi [wn * 128 + row] = ti [m * 4 + r];
            }
    }
    __syncthreads();
    if (tid < 128) {
        float m1 = mm1[tid], m2 = mm2[tid]; int i1 = mi[tid];
        float b1 = mm1[128 + tid], b2 = mm2[128 + tid]; int bi = mi[128 + tid];
        if (b1 < m1 || (b1 == m1 && bi < i1)) { m2 = fminf(m1, b2); m1 = b1; i1 = bi; }
        else m2 = fminf(m2, b1);
        size_t gr = (size_t)bn * T_ + (size_t)bx * 128 + tid;
        pm1[gr * 8 + by] = m1; pm2[gr * 8 + by] = m2; pi1[gr * 8 + by] = i1;
    }
}

// ----------------------------------------- finalize: merge, flag, fast loss
__global__ __launch_bounds__(256) void finalize_kernel(
    const float* __restrict__ pm1, const float* __restrict__ pm2,
    const int* __restrict__ pi1,
    float* __restrict__ outc, float* __restrict__ lossp,
    int* __restrict__ flag_cnt, int* __restrict__ flag_list) {
    int row = blockIdx.x * 256 + threadIdx.x;   // ROWS_ exact
    size_t r8 = (size_t)row * 8;
    float m1 = pm1[r8], m2 = pm2[r8]; int i1 = pi1[r8];
#pragma unroll
    for (int j = 1; j < 8; ++j) {
        float b1 = pm1[r8 + j], b2 = pm2[r8 + j]; int bi = pi1[r8 + j];
        if (b1 < m1) { m2 = fminf(m1, b2); m1 = b1; i1 = bi; }
        else m2 = fminf(m2, b1);
    }
    float lrow = m1;   // x^2 part already accumulated by convert_all
    if (m2 - m1 < MARGIN_) {
        int slot = atomicAdd(flag_cnt, 1);
        if (slot < FLAGCAP_) { flag_list[slot] = row; lrow = 0.f; }
        else outc[row] = (float)i1;   // overflow fallback (practically impossible)
    } else {
        outc[row] = (float)i1;
    }
    for (int off = 32; off > 0; off >>= 1) lrow += __shfl_down(lrow, off, 64);
    __shared__ float ws4[4];
    if ((threadIdx.x & 63) == 0) ws4[threadIdx.x >> 6] = lrow;
    __syncthreads();
    if (threadIdx.x == 0)
        atomicAdd(lossp, (ws4[0] + ws4[1] + ws4[2] + ws4[3]) * QSCALE_);
}

// --------------- rescan flagged rows exactly (fp64) over candidate tiles
__global__ __launch_bounds__(256) void rescan_kernel(
    const float* __restrict__ x, const float* __restrict__ cb,
    const float* __restrict__ pm1,
    const int* __restrict__ flag_cnt, const int* __restrict__ flag_list,
    float* __restrict__ outc, float* __restrict__ lossp) {
    int tid = threadIdx.x;
    int cnt = *flag_cnt; if (cnt > FLAGCAP_) cnt = FLAGCAP_;
    __shared__ float xsh[D_];
    __shared__ float qm[8];
    __shared__ double rv[256];
    __shared__ int    ri[256];
    for (int i = blockIdx.x; i < cnt; i += RESCAN_BLOCKS_) {
        int row = flag_list[i];
        int bn = row / T_, t = row % T_;
        int band = bn % NB_;
        __syncthreads();
        if (tid < 8) qm[tid] = pm1[(size_t)row * 8 + tid];
        for (int d = tid; d < D_; d += 256)
            xsh[d] = x[((size_t)bn * D_ + d) * T_ + t];
        __syncthreads();
        float gmin = qm[0];
#pragma unroll
        for (int j = 1; j < 8; ++j) gmin = fminf(gmin, qm[j]);
        // exact row x^2 (to back out convert_all's contribution)
        double px2 = 0.0;
        for (int d = tid; d < D_; d += 256) px2 += (double)xsh[d] * (double)xsh[d];
        rv[tid] = px2;
        __syncthreads();
        for (int s2 = 128; s2 > 0; s2 >>= 1) {
            if (tid < s2) rv[tid] += rv[tid + s2];
            __syncthreads();
        }
        double x2row = rv[0];
        __syncthreads();

        int kq = tid >> 1, half = tid & 1;
        double best = 1e300; int bi = K_;
        for (int j = 0; j < 8; ++j) {
            if (qm[j] > gmin + WINDOW_) continue;   // uniform branch (shared)
            int k = j * 128 + kq;
            const float* cr = cb + ((size_t)band * K_ + k) * D_ + half * 256;
            const float* xr = xsh + half * 256;
            double s = 0.0;
#pragma unroll 4
            for (int d = 0; d < 256; d += 4) {
                float4 c4 = *(const float4*)(cr + d);
                double e0 = (double)xr[d]     - (double)c4.x;
                double e1 = (double)xr[d + 1] - (double)c4.y;
                double e2v = (double)xr[d + 2] - (double)c4.z;
                double e3 = (double)xr[d + 3] - (double)c4.w;
                s += e0 * e0 + e1 * e1 + e2v * e2v + e3 * e3;
            }
            s += __shfl_xor(s, 1, 64);   // combine halves; both lanes hold full dist
            if (s < best || (s == best && k < bi)) { best = s; bi = k; }
        }
        rv[tid] = best; ri[tid] = bi;
        __syncthreads();
        for (int s2 = 128; s2 > 0; s2 >>= 1) {
            if (tid < s2) {
                if (rv[tid + s2] < rv[tid] ||
                    (rv[tid + s2] == rv[tid] && ri[tid + s2] < ri[tid])) {
                    rv[tid] = rv[tid + s2]; ri[tid] = ri[tid + s2];
                }
            }
            __syncthreads();
        }
        if (tid == 0) {
            outc[row] = (float)ri[0];
            atomicAdd(lossp, (float)((rv[0] - x2row) * (double)QSCALE_));
        }
        __syncthreads();
    }
}

// ------------------- gather + write outq: 256t x 16d blocks, 1KB HBM runs
__global__ __launch_bounds__(256) void gather_out(
    const float* __restrict__ cb, const float* __restrict__ outc,
    float* __restrict__ outq) {
    int t0 = blockIdx.x * 256;   // 8
    int d0 = blockIdx.y * 16;    // 32
    int bn = blockIdx.z;         // 24
    int band = bn % NB_;
    int tid = threadIdx.x;
    __shared__ int csh[256];
    __shared__ float qsh[16][260];   // [d][t]
    csh[tid] = (int)outc[(size_t)bn * T_ + t0 + tid];
    __syncthreads();
    const float* cbb = cb + (size_t)band * K_ * D_ + d0;
    int tq = tid >> 2, dq = (tid & 3) * 4;
#pragma unroll
    for (int p = 0; p < 4; ++p) {
        int t = tq + p * 64;
        float4 v = *(const float4*)(cbb + (size_t)csh[t] * D_ + dq);
        qsh[dq + 0][t] = v.x; qsh[dq + 1][t] = v.y;
        qsh[dq + 2][t] = v.z; qsh[dq + 3][t] = v.w;
    }
    __syncthreads();
    int wv = tid >> 6, ln = tid & 63;
#pragma unroll
    for (int j = 0; j < 4; ++j) {
        int dd = wv * 4 + j;
        *(float4*)&outq[((size_t)bn * D_ + d0 + dd) * T_ + t0 + ln * 4] =
            *(const float4*)&qsh[dd][ln * 4];
    }
}

// ---------------------------------------------------------------- launcher
extern "C" void kernel_launch(void* const* d_in, const int* in_sizes, int n_in,
                              void* d_out, int out_size, void* d_ws, size_t ws_size,
                              hipStream_t stream) {
    (void)in_sizes; (void)n_in; (void)out_size; (void)ws_size;
    const float* x  = (const float*)d_in[0];
    const float* cb = (const float*)d_in[1];
    float* out = (float*)d_out;

    float* outq  = out;                       // [B,NB,D,T]
    float* outc  = out + Q_ELEMS_;            // [B,NB,T] as float
    float* lossp = out + Q_ELEMS_ + ROWS_;    // scalar

    // f16 x lives in the (not-yet-written) quantized output region (50.3 MB =
    // first 12,582,912 floats). GEMM partials live after it, also inside outq
    // (read by finalize/rescan, overwritten only by gather_out at the end).
    unsigned short* Xh = (unsigned short*)d_out;
    float* pm1 = out + 13107200;                   // 393216 floats
    float* pm2 = pm1 + (size_t)ROWS_ * 8;          // 393216
    int*   pi1 = (int*)(pm2 + (size_t)ROWS_ * 8);  // 393216 (ends ~14.3M < 25.1M)

    char* ws = (char*)d_ws;
    unsigned short* Eh = (unsigned short*)ws;                    // 3 MiB
    float* e2  = (float*)(Eh + (size_t)NB_ * K_ * D_);           // 12 KiB
    int*   flag_cnt  = (int*)(e2 + NB_ * K_);                    // 4 B
    int*   flag_list = flag_cnt + 1;                             // 32 KiB

    convert_all<<<dim3(32, 9, 24), dim3(256), 0, stream>>>(
        x, cb, Xh, Eh, e2, lossp, flag_cnt);
    vq_gemm<<<dim3(16, 8, 24), dim3(256), 0, stream>>>(Xh, Eh, e2, pm1, pm2, pi1);
    finalize_kernel<<<dim3(ROWS_ / 256), dim3(256), 0, stream>>>(
        pm1, pm2, pi1, outc, lossp, flag_cnt, flag_list);
    rescan_kernel<<<dim3(RESCAN_BLOCKS_), dim3(256), 0, stream>>>(
        x, cb, pm1, flag_cnt, flag_list, outc, lossp);
    gather_out<<<dim3(8, 32, 24), dim3(256), 0, stream>>>(cb, outc, outq);
}